// Round 9
// baseline (2078.304 us; speedup 1.0000x reference)
//
#include <hip/hip_runtime.h>
#include <stdint.h>

// Experts MLP: out[b,e] = gelu(x[b,e] @ w1[e] + b1[e]) @ w2[e] + b2[e]
// B=4 E=8 N=1024 D=1024 H=4096.
// Round 9: 4-interval tile, reads UNDER MFMA. Every interval: [stages;
// ds_reads for a future cluster; sched_barrier(0); 16 MFMA on regs]. The
// 12-read afL'/bf0' batch hides under q10 (register-only consumer). B-frag
// arrays ping-pong ROLES per tile (bf0(kt+1) lands in bf1(kt)'s dead regs)
// -> zero VGPR growth (r8's 128+128 two-wave boundary preserved).
// Waits: vmcnt(2) end-I1 (drain A-hi(kt)), vmcnt(2) end-I3 (drain all of
// buf(kt+1) except A-hi(kt+1), staged last). Barriers: 4/tile (was 8).

typedef __attribute__((ext_vector_type(8))) short short8;
typedef __attribute__((ext_vector_type(4))) float f32x4;

__device__ __forceinline__ unsigned short f2b(float f){
  union { float f; unsigned int u; } v; v.f = f;
  unsigned int r = v.u + 0x7fffu + ((v.u >> 16) & 1u);   // RNE
  return (unsigned short)(r >> 16);
}

// tanh-form GELU via exp2/rcp (verified r3-r8)
__device__ __forceinline__ float gelu_fast(float v){
  float v2 = v * v;
  float w = v * (-2.302217529693f + -0.102943795894f * v2);
  float e = __builtin_amdgcn_exp2f(w);
  return v * __builtin_amdgcn_rcpf(1.0f + e);
}

__device__ __forceinline__ void glds16(const void* g, const void* l){
  __builtin_amdgcn_global_load_lds((const __attribute__((address_space(1))) uint32_t*)g,
                                   (__attribute__((address_space(3))) uint32_t*)l, 16, 0, 0);
}

#define BAR() do{ asm volatile("" ::: "memory"); __builtin_amdgcn_s_barrier(); asm volatile("" ::: "memory"); }while(0)
#define VMW(N) do{ if ((N)==2) asm volatile("s_waitcnt vmcnt(2)":::"memory"); \
  else if ((N)==0) asm volatile("s_waitcnt vmcnt(0)":::"memory"); }while(0)
#define SCHEDPIN() __builtin_amdgcn_sched_barrier(0)

// ---------------- prep kernels (verified r1-r8) ----------------

__global__ void cvt_x_kernel(const float* __restrict__ src, unsigned short* __restrict__ dst, int n4){
  int i = blockIdx.x * blockDim.x + threadIdx.x;
  int stride = gridDim.x * blockDim.x;
  for (; i < n4; i += stride){
    float4 v = ((const float4*)src)[i];
    ushort4 o;
    o.x = f2b(v.x); o.y = f2b(v.y); o.z = f2b(v.z); o.w = f2b(v.w);
    ((ushort4*)dst)[i] = o;
  }
}

__global__ void transpose_cvt(const float* __restrict__ src, unsigned short* __restrict__ dst, int R, int C){
  __shared__ float t[64][65];
  const int e = blockIdx.z;
  src += (size_t)e * R * C;
  dst += (size_t)e * R * C;
  const int r0 = blockIdx.y * 64, c0 = blockIdx.x * 64;
  const int tid = threadIdx.x;
  const int lr = tid >> 4;
  const int lc4 = (tid & 15) * 4;
  #pragma unroll
  for (int p2 = 0; p2 < 4; p2++){
    int r = lr + p2 * 16;
    float4 v = *(const float4*)(src + (size_t)(r0 + r) * C + (c0 + lc4));
    t[r][lc4+0] = v.x; t[r][lc4+1] = v.y; t[r][lc4+2] = v.z; t[r][lc4+3] = v.w;
  }
  __syncthreads();
  #pragma unroll
  for (int p2 = 0; p2 < 4; p2++){
    int c = lr + p2 * 16;
    ushort4 o;
    o.x = f2b(t[lc4+0][c]); o.y = f2b(t[lc4+1][c]);
    o.z = f2b(t[lc4+2][c]); o.w = f2b(t[lc4+3][c]);
    *(ushort4*)(dst + (size_t)(c0 + c) * R + (r0 + lc4)) = o;
  }
}

// ---------------- 256x256 4-interval GEMM, reads under MFMA ----------------
// LDS rows = 64 bf16 (8 x 16B chunks); chunk c of row r at LDS chunk
// (c ^ (r&7)); LDS linear + pre-swizzled global source (rule #21).
// LDS map (shorts): A buf0 @0, A buf1 @16384, B buf0 @32768, B buf1 @49152.
// Intervals per tile kt (barrier after each):
//  I1: stage B-lo(kt+1); read bf1(kt);      PIN; q00 = afL x bf0; vmcnt(2)
//  I2: stage B-hi(kt+1); read afH(kt);      PIN; q01 = afL x bf1
//  I3: stage A-lo(kt+1), A-hi(kt+1);        PIN; q11 = afH x bf1; vmcnt(2)
//  I4: read afL(kt+1), bf0(kt+1) [other buf]; PIN; q10 = afH x bf0
// Cross-wave visibility: each staged block's writer-wave drains its own
// vmcnt >=1 interval + 1 barrier before any reader's ds_read (audited).
// bf0(kt+1) lands in bf1(kt)'s registers (dead after q11): B arrays swap
// roles each tile via the parity-unrolled loop.

template<int PHASE1>
__global__ __launch_bounds__(512, 2) void gemm256(
    const unsigned short* __restrict__ A,
    const unsigned short* __restrict__ Bt,
    const float* __restrict__ bias,
    void* __restrict__ Out,
    int p0)
{
  constexpr int M  = 1024;
  constexpr int K  = PHASE1 ? 1024 : 4096;
  constexpr int Nd = PHASE1 ? 4096 : 1024;
  constexpr int TM = M / 256, TN = Nd / 256;
  constexpr int NT = K / 64;                 // 16 or 64 (even, >=4)

  const int cpx = gridDim.x >> 3;
  const int bid = (blockIdx.x & 7) * cpx + (blockIdx.x >> 3);
  const int tn = bid % TN;
  const int t2 = bid / TN;
  const int tm = t2 % TM;
  const int cp = t2 / TM;
  const int p  = p0 + cp, e = p & 7;
  const int m0 = tm * 256, n0 = tn * 256;

  const unsigned short* Ag = A  + (size_t)(PHASE1 ? p : cp) * M * K + (size_t)m0 * K;
  const unsigned short* Bg = Bt + (size_t)e * Nd * K + (size_t)n0 * K;
  const float*          bp = bias + (size_t)e * Nd;

  __shared__ __align__(16) unsigned short lds[65536];

  const int tid = threadIdx.x;
  const int w = tid >> 6, lane = tid & 63;
  const int wr = w >> 2, wc = w & 3;          // 2 x 4 waves; wave tile 128 x 64
  const int c15 = lane & 15, q = lane >> 4;

  // staging: per-thread row within a 64-row block + swizzled chunk (shorts)
  const int trow = (w << 3) + (lane >> 3);                 // 0..63
  const int scol = ((lane & 7) ^ (trow & 7)) << 3;
  const unsigned short* pA0 = Ag + (size_t)(trow       ) * K + scol;
  const unsigned short* pA1 = Ag + (size_t)(trow +  64) * K + scol;
  const unsigned short* pA2 = Ag + (size_t)(trow + 128) * K + scol;
  const unsigned short* pA3 = Ag + (size_t)(trow + 192) * K + scol;
  const unsigned short* pB0 = Bg + (size_t)(trow       ) * K + scol;
  const unsigned short* pB1 = Bg + (size_t)(trow +  64) * K + scol;
  const unsigned short* pB2 = Bg + (size_t)(trow + 128) * K + scol;
  const unsigned short* pB3 = Bg + (size_t)(trow + 192) * K + scol;
  const int wof = w << 9;                                  // LDS dest base (shorts)

  // frag-read per-thread constants (shorts)
  const int rA64 = (wr * 128 + c15) << 6;
  const int rB64 = (wc * 64  + c15) << 6;
  const int cx0 = ( q      ^ (c15 & 7)) << 3;              // kk=0 chunk
  const int cx1 = ((q ^ 4) ^ (c15 & 7)) << 3;              // kk=1 chunk

  // bias folded into accumulator init
  float bv[4];
  #pragma unroll
  for (int nf = 0; nf < 4; ++nf) bv[nf] = bp[n0 + wc * 64 + nf * 16 + c15];

  f32x4 acc[8][4];
  #pragma unroll
  for (int i = 0; i < 8; i++)
    #pragma unroll
    for (int j = 0; j < 4; j++) acc[i][j] = (f32x4)(bv[j]);

  short8 afL[4][2], afH[4][2], bfX[2][2], bfY[2][2];

#define LDS8(OFS) (*(const short8*)(lds + (OFS)))
#define RD_A(DST, BASE) do{ _Pragma("unroll") for (int mf = 0; mf < 4; ++mf){ \
    DST[mf][0] = LDS8((BASE) + rA64 + mf * 1024 + cx0); \
    DST[mf][1] = LDS8((BASE) + rA64 + mf * 1024 + cx1); } }while(0)
#define RD_B(DST, BASE) do{ _Pragma("unroll") for (int nf = 0; nf < 2; ++nf){ \
    DST[nf][0] = LDS8((BASE) + rB64 + nf * 1024 + cx0); \
    DST[nf][1] = LDS8((BASE) + rB64 + nf * 1024 + cx1); } }while(0)
#define Q8(MO,NO,AF,BF) do{ _Pragma("unroll") for (int mi = 0; mi < 4; ++mi) \
    _Pragma("unroll") for (int nf = 0; nf < 2; ++nf){ \
      acc[(MO)+mi][(NO)+nf] = __builtin_amdgcn_mfma_f32_16x16x32_bf16(AF[mi][0], BF[nf][0], acc[(MO)+mi][(NO)+nf], 0, 0, 0); \
      acc[(MO)+mi][(NO)+nf] = __builtin_amdgcn_mfma_f32_16x16x32_bf16(AF[mi][1], BF[nf][1], acc[(MO)+mi][(NO)+nf], 0, 0, 0); } }while(0)

  // ---- prologue: tile0 full (B then A-lo then A-hi); keep A-hi in flight ----
  glds16(pB0, lds + wof + 32768);
  glds16(pB1, lds + wof + 32768 + 4096);
  glds16(pB2, lds + wof + 32768 + 8192);
  glds16(pB3, lds + wof + 32768 + 12288);
  glds16(pA0, lds + wof);
  glds16(pA2, lds + wof + 8192);
  glds16(pA1, lds + wof + 4096);
  glds16(pA3, lds + wof + 12288);
  VMW(2);                      // drain B(0)+A-lo(0); A-hi(0) stays in flight
  BAR();
  RD_A(afL, 0);                // afL(0)
  RD_B(bfX, 32768);            // bf0(0)

  // One K-tile. CB parity selects LDS buf AND B-array roles.
  // STG: stage tile kt+1. RDN: read afL/bf0 of kt+1 in I4.
  // W1: vmcnt at end I1 (2 normal, 0 at NT-1). W3: 1 -> vmcnt(2) at end I3.
#define TILE_N(CB, STG, RDN, W1, W3) do{                                        \
    constexpr int AB  = (CB) * 16384;                                           \
    constexpr int BB  = 32768 + (CB) * 16384;                                   \
    constexpr int ABn = ((CB) ^ 1) * 16384;                                     \
    constexpr int BBn = 32768 + (((CB) ^ 1) * 16384);                           \
    constexpr int O1  = (CB) ? 128 : 64;                                        \
    auto& BF0 = (CB) ? bfY : bfX;   /* holds bf0(kt) */                         \
    auto& BF1 = (CB) ? bfX : bfY;   /* gets bf1(kt), then bf0(kt+1) */          \
    /* I1: stage B-lo(kt+1); read bf1(kt); q00 = afL x bf0 */                   \
    if (STG){ glds16(pB0 + O1, lds + BBn + wof);                                \
              glds16(pB1 + O1, lds + BBn + 4096 + wof); }                       \
    RD_B(BF1, BB + 2048);                                                       \
    SCHEDPIN();                                                                 \
    __builtin_amdgcn_s_setprio(1);                                              \
    Q8(0, 0, afL, BF0);                                                         \
    __builtin_amdgcn_s_setprio(0);                                              \
    VMW(W1);                                                                    \
    BAR();                                                                      \
    /* I2: stage B-hi(kt+1); read afH(kt); q01 = afL x bf1 */                   \
    if (STG){ glds16(pB2 + O1, lds + BBn + 8192 + wof);                         \
              glds16(pB3 + O1, lds + BBn + 12288 + wof); }                      \
    RD_A(afH, AB + 4096);                                                       \
    SCHEDPIN();                                                                 \
    __builtin_amdgcn_s_setprio(1);                                              \
    Q8(0, 2, afL, BF1);                                                         \
    __builtin_amdgcn_s_setprio(0);                                              \
    BAR();                                                                      \
    /* I3: stage A-lo(kt+1) then A-hi(kt+1); q11 = afH x bf1 */                 \
    if (STG){ glds16(pA0 + O1, lds + ABn + wof);                                \
              glds16(pA2 + O1, lds + ABn + 8192 + wof);                         \
              glds16(pA1 + O1, lds + ABn + 4096 + wof);                         \
              glds16(pA3 + O1, lds + ABn + 12288 + wof); }                      \
    SCHEDPIN();                                                                 \
    __builtin_amdgcn_s_setprio(1);                                              \
    Q8(4, 2, afH, BF1);                                                         \
    __builtin_amdgcn_s_setprio(0);                                              \
    if (W3){ VMW(2); }   /* drain B(kt+1)+A-lo(kt+1); keep A-hi(kt+1) */        \
    BAR();                                                                      \
    /* I4: read afL(kt+1), bf0(kt+1) -> BF1 regs (dead); q10 = afH x bf0 */     \
    if (RDN){ RD_A(afL, ABn); RD_B(BF1, BBn); }                                 \
    SCHEDPIN();                                                                 \
    __builtin_amdgcn_s_setprio(1);                                              \
    Q8(4, 0, afH, BF0);                                                         \
    __builtin_amdgcn_s_setprio(0);                                              \
    BAR();                                                                      \
  }while(0)

  for (int kt2 = 0; kt2 < NT - 2; kt2 += 2){
    TILE_N(0, 1, 1, 2, 1);
    TILE_N(1, 1, 1, 2, 1);
    pA0 += 128; pA1 += 128; pA2 += 128; pA3 += 128;
    pB0 += 128; pB1 += 128; pB2 += 128; pB3 += 128;
  }
  TILE_N(0, 1, 1, 2, 1);     // kt = NT-2: stages + reads tile NT-1 frags
  TILE_N(1, 0, 0, 0, 0);     // kt = NT-1: compute only; vmcnt(0) at I1
#undef TILE_N

  // ---- epilogue: C/D layout col = lane&15, row = (lane>>4)*4 + r ----
  #pragma unroll
  for (int mf = 0; mf < 8; ++mf){
    const int row = m0 + wr * 128 + mf * 16 + q * 4;
    #pragma unroll
    for (int nf = 0; nf < 4; ++nf){
      const int col = n0 + wc * 64 + nf * 16 + c15;
      #pragma unroll
      for (int r = 0; r < 4; ++r){
        float v = acc[mf][nf][r];
        if constexpr (PHASE1){
          ((unsigned short*)Out)[(size_t)cp * M * Nd + (size_t)(row + r) * Nd + col] = f2b(gelu_fast(v));
        } else {
          ((float*)Out)[(size_t)p * M * Nd + (size_t)(row + r) * Nd + col] = v;
        }
      }
    }
  }
}

// ---------------- launch ----------------

extern "C" void kernel_launch(void* const* d_in, const int* in_sizes, int n_in,
                              void* d_out, int out_size, void* d_ws, size_t ws_size,
                              hipStream_t stream){
  const float* x  = (const float*)d_in[0];
  const float* w1 = (const float*)d_in[1];
  const float* b1 = (const float*)d_in[2];
  const float* w2 = (const float*)d_in[3];
  const float* b2 = (const float*)d_in[4];
  float* out = (float*)d_out;

  unsigned short* xb  = (unsigned short*)d_ws;
  unsigned short* w1t = (unsigned short*)((char*)d_ws + ((size_t)64  << 20));
  unsigned short* w2t = (unsigned short*)((char*)d_ws + ((size_t)128 << 20));
  unsigned short* hb  = (unsigned short*)((char*)d_ws + ((size_t)192 << 20));

  size_t avail = ws_size > ((size_t)192 << 20) ? ws_size - ((size_t)192 << 20) : 0;
  int ppc = (int)(avail / ((size_t)8 << 20));
  if (ppc > 32) ppc = 32;
  if (ppc < 1) return;

  cvt_x_kernel<<<2048, 256, 0, stream>>>(x, xb, 8 * 1024 * 1024);
  transpose_cvt<<<dim3(64, 16, 8), 256, 0, stream>>>(w1, w1t, 1024, 4096);
  transpose_cvt<<<dim3(16, 64, 8), 256, 0, stream>>>(w2, w2t, 4096, 1024);

  for (int p0 = 0; p0 < 32; p0 += ppc){
    int np = (32 - p0 < ppc) ? (32 - p0) : ppc;
    // GEMM1: h = gelu(xb @ w1t^T + b1)   [M=1024, K=1024, Nd=4096]
    gemm256<1><<<dim3(np * 4 * 16), 512, 0, stream>>>(xb, w1t, b1, hb, p0);
    // GEMM2: out = h @ w2t^T + b2        [M=1024, K=4096, Nd=1024]
    gemm256<0><<<dim3(np * 4 * 4),  512, 0, stream>>>(hb, w2t, b2, out, p0);
  }
}

// Round 10
// 695.492 us; speedup vs baseline: 2.9883x; 2.9883x over previous
//
#include <hip/hip_runtime.h>
#include <stdint.h>

// Experts MLP: out[b,e] = gelu(x[b,e] @ w1[e] + b1[e]) @ w2[e] + b2[e]
// B=4 E=8 N=1024 D=1024 H=4096.
// Round 10: r8's verified skeleton (staging order, chunk-XOR swizzle, vmcnt
// codes, 8 barriers/tile) with the MFMA shape swapped 16x16x32 -> 32x32x16
// (µbench 2495 vs 2075 TF, half the instruction count). Frag register budget
// IDENTICAL to r8 (af 8 b128 reused lo->hi, bf0/bf1 4 each = 64 VGPR; acc
// 8 x f32x16 = 128) -- r9 proved 256 regs/wave is a hard wall at 8 waves/CU.

typedef __attribute__((ext_vector_type(8))) short short8;
typedef __attribute__((ext_vector_type(16))) float f32x16;

__device__ __forceinline__ unsigned short f2b(float f){
  union { float f; unsigned int u; } v; v.f = f;
  unsigned int r = v.u + 0x7fffu + ((v.u >> 16) & 1u);   // RNE
  return (unsigned short)(r >> 16);
}

// tanh-form GELU via exp2/rcp (verified r3-r8)
__device__ __forceinline__ float gelu_fast(float v){
  float v2 = v * v;
  float w = v * (-2.302217529693f + -0.102943795894f * v2);
  float e = __builtin_amdgcn_exp2f(w);
  return v * __builtin_amdgcn_rcpf(1.0f + e);
}

__device__ __forceinline__ void glds16(const void* g, const void* l){
  __builtin_amdgcn_global_load_lds((const __attribute__((address_space(1))) uint32_t*)g,
                                   (__attribute__((address_space(3))) uint32_t*)l, 16, 0, 0);
}

#define BAR() do{ asm volatile("" ::: "memory"); __builtin_amdgcn_s_barrier(); asm volatile("" ::: "memory"); }while(0)
#define VMW(N) do{ if ((N)==6) asm volatile("s_waitcnt vmcnt(6)":::"memory"); \
  else if ((N)==4) asm volatile("s_waitcnt vmcnt(4)":::"memory"); \
  else if ((N)==2) asm volatile("s_waitcnt vmcnt(2)":::"memory"); \
  else if ((N)==0) asm volatile("s_waitcnt vmcnt(0)":::"memory"); }while(0)

// ---------------- prep kernels (verified r1-r8) ----------------

__global__ void cvt_x_kernel(const float* __restrict__ src, unsigned short* __restrict__ dst, int n4){
  int i = blockIdx.x * blockDim.x + threadIdx.x;
  int stride = gridDim.x * blockDim.x;
  for (; i < n4; i += stride){
    float4 v = ((const float4*)src)[i];
    ushort4 o;
    o.x = f2b(v.x); o.y = f2b(v.y); o.z = f2b(v.z); o.w = f2b(v.w);
    ((ushort4*)dst)[i] = o;
  }
}

__global__ void transpose_cvt(const float* __restrict__ src, unsigned short* __restrict__ dst, int R, int C){
  __shared__ float t[64][65];
  const int e = blockIdx.z;
  src += (size_t)e * R * C;
  dst += (size_t)e * R * C;
  const int r0 = blockIdx.y * 64, c0 = blockIdx.x * 64;
  const int tid = threadIdx.x;
  const int lr = tid >> 4;
  const int lc4 = (tid & 15) * 4;
  #pragma unroll
  for (int p2 = 0; p2 < 4; p2++){
    int r = lr + p2 * 16;
    float4 v = *(const float4*)(src + (size_t)(r0 + r) * C + (c0 + lc4));
    t[r][lc4+0] = v.x; t[r][lc4+1] = v.y; t[r][lc4+2] = v.z; t[r][lc4+3] = v.w;
  }
  __syncthreads();
  #pragma unroll
  for (int p2 = 0; p2 < 4; p2++){
    int c = lr + p2 * 16;
    ushort4 o;
    o.x = f2b(t[lc4+0][c]); o.y = f2b(t[lc4+1][c]);
    o.z = f2b(t[lc4+2][c]); o.w = f2b(t[lc4+3][c]);
    *(ushort4*)(dst + (size_t)(c0 + c) * R + (r0 + lc4)) = o;
  }
}

// ---------------- 256x256 8-phase GEMM, 32x32x16 MFMA ----------------
// LDS rows = 64 bf16 (8 x 16B chunks); chunk c of row r at LDS chunk
// (c ^ (r&7)); LDS linear + pre-swizzled global source (rule #21).
// LDS map (shorts): A buf0 @0, A buf1 @16384, B buf0 @32768, B buf1 @49152.
// 32x32x16 frags: A lane holds row (lane&31), k-elems (lane>>5)*8 within each
// K=16 step; K-tile 64 = 4 ksteps; chunk(ks) = ks*2 + (lane>>5).
// C/D: col = lane&31, row = (reg&3) + 8*(reg>>2) + 4*(lane>>5)  [m74/m101].
// Wave tile 128x64 = 4 rowblocks(32) x 2 colblocks(32); 32 MFMA/wave/K-tile.
// Intervals per tile kt (identical sync skeleton to r8):
//   I_a: read af<-A rb0-1(kt), bf0(kt); stage B-lo(kt+1)         [no wait]
//   I_b: read bf1(kt); stage B-hi(kt+1); G(rb0-1,cb0);           vmcnt(6)
//   I_c: G(rb0-1,cb1); read af<-A rb2-3(kt); stage A-hi(kt+1)    [no wait]
//   I_d: stage A-lo(kt+2); G(rb2-3,cb1); G(rb2-3,cb0);           vmcnt(4)

template<int PHASE1>
__global__ __launch_bounds__(512, 2) void gemm256(
    const unsigned short* __restrict__ A,
    const unsigned short* __restrict__ Bt,
    const float* __restrict__ bias,
    void* __restrict__ Out,
    int p0)
{
  constexpr int M  = 1024;
  constexpr int K  = PHASE1 ? 1024 : 4096;
  constexpr int Nd = PHASE1 ? 4096 : 1024;
  constexpr int TM = M / 256, TN = Nd / 256;
  constexpr int NT = K / 64;                 // 16 or 64 (even, >=4)

  const int cpx = gridDim.x >> 3;
  const int bid = (blockIdx.x & 7) * cpx + (blockIdx.x >> 3);
  const int tn = bid % TN;
  const int t2 = bid / TN;
  const int tm = t2 % TM;
  const int cp = t2 / TM;
  const int p  = p0 + cp, e = p & 7;
  const int m0 = tm * 256, n0 = tn * 256;

  const unsigned short* Ag = A  + (size_t)(PHASE1 ? p : cp) * M * K + (size_t)m0 * K;
  const unsigned short* Bg = Bt + (size_t)e * Nd * K + (size_t)n0 * K;
  const float*          bp = bias + (size_t)e * Nd;

  __shared__ __align__(16) unsigned short lds[65536];

  const int tid = threadIdx.x;
  const int w = tid >> 6, lane = tid & 63;
  const int wr = w >> 2, wc = w & 3;          // 2 x 4 waves; wave tile 128 x 64
  const int l31 = lane & 31, hi = lane >> 5;

  // staging: per-thread row within a 64-row block + swizzled chunk (shorts)
  const int trow = (w << 3) + (lane >> 3);                 // 0..63
  const int scol = ((lane & 7) ^ (trow & 7)) << 3;
  const unsigned short* pA0 = Ag + (size_t)(trow       ) * K + scol;
  const unsigned short* pA1 = Ag + (size_t)(trow +  64) * K + scol;
  const unsigned short* pA2 = Ag + (size_t)(trow + 128) * K + scol;
  const unsigned short* pA3 = Ag + (size_t)(trow + 192) * K + scol;
  const unsigned short* pB0 = Bg + (size_t)(trow       ) * K + scol;
  const unsigned short* pB1 = Bg + (size_t)(trow +  64) * K + scol;
  const unsigned short* pB2 = Bg + (size_t)(trow + 128) * K + scol;
  const unsigned short* pB3 = Bg + (size_t)(trow + 192) * K + scol;
  const int wof = w << 9;                                  // LDS dest base (shorts)

  // frag-read per-thread constants (shorts). row&7 == lane&7 for all frag rows.
  const int rA32 = (wr * 128 + l31) << 6;                  // A row base offset
  const int rB32 = (wc * 64  + l31) << 6;                  // B row base offset
  int cc[4];
  #pragma unroll
  for (int ks = 0; ks < 4; ++ks) cc[ks] = (((ks << 1) + hi) ^ (lane & 7)) << 3;

  // bias folded into accumulator init (col = lane-constant per colblock)
  float bv0 = bp[n0 + wc * 64      + l31];
  float bv1 = bp[n0 + wc * 64 + 32 + l31];

  f32x16 acc[4][2];
  #pragma unroll
  for (int rb = 0; rb < 4; rb++){ acc[rb][0] = (f32x16)(bv0); acc[rb][1] = (f32x16)(bv1); }

  // ---- prologue: tile0 (A+B) into buf0; A-lo(tile1) into buf1 (as r8) ----
  glds16(pA0, lds + wof);
  glds16(pA1, lds + wof + 4096);
  glds16(pA2, lds + wof + 8192);
  glds16(pA3, lds + wof + 12288);
  glds16(pB0, lds + wof + 32768);
  glds16(pB1, lds + wof + 32768 + 4096);
  glds16(pB2, lds + wof + 32768 + 8192);
  glds16(pB3, lds + wof + 32768 + 12288);
  glds16(pA0 + 64, lds + wof + 16384);            // A-lo(1): rows 0-63
  glds16(pA2 + 64, lds + wof + 16384 + 8192);     // A-lo(1): rows 128-191
  asm volatile("s_waitcnt vmcnt(2)" ::: "memory");
  BAR();

  short8 af[2][4], bf0[4], bf1[4];

  // read A rowblock pair {RB0, RB0+1} (8 b128) ; rowblock stride = 2048 shorts
#define RD_A(BASE, RB0) do{ _Pragma("unroll") for (int rb2 = 0; rb2 < 2; ++rb2) \
    _Pragma("unroll") for (int ks = 0; ks < 4; ++ks) \
      af[rb2][ks] = *(const short8*)(lds + (BASE) + rA32 + ((RB0) + rb2) * 2048 + cc[ks]); }while(0)
#define RD_B(DST, BASE, CB) do{ _Pragma("unroll") for (int ks = 0; ks < 4; ++ks) \
    DST[ks] = *(const short8*)(lds + (BASE) + rB32 + (CB) * 2048 + cc[ks]); }while(0)
  // 8 MFMA: rowblocks {RB0,RB0+1} x colblock CB x 4 ksteps
#define QG(RB0, CB, BF) do{ _Pragma("unroll") for (int rb2 = 0; rb2 < 2; ++rb2) \
    _Pragma("unroll") for (int ks = 0; ks < 4; ++ks) \
      acc[(RB0) + rb2][CB] = __builtin_amdgcn_mfma_f32_32x32x16_bf16(af[rb2][ks], BF[ks], acc[(RB0) + rb2][CB], 0, 0, 0); }while(0)

  // One K-tile. SB1: stage tile kt+1 (B + A-hi). SA2: stage A-lo(kt+2).
  // WB/WD: vmcnt codes at I_b/I_d ends (-1 = none). Same codes as r8.
#define TILE_P(CB_, SB1, SA2, WB, WD) do{                                       \
    constexpr int AB  = (CB_) * 16384;                                          \
    constexpr int BB  = 32768 + (CB_) * 16384;                                  \
    constexpr int ABn = ((CB_) ^ 1) * 16384;                                    \
    constexpr int BBn = 32768 + (((CB_) ^ 1) * 16384);                          \
    constexpr int O1  = (CB_) ? 128 : 64;                                       \
    constexpr int O2  = (CB_) ? 192 : 128;                                      \
    /* I_a: read af<-A rb0-1(kt), bf0(kt); stage B-lo(kt+1) */                  \
    RD_A(AB, 0);                                                                \
    RD_B(bf0, BB, 0);                                                           \
    if (SB1){ glds16(pB0 + O1, lds + BBn + wof);                                \
              glds16(pB1 + O1, lds + BBn + 4096 + wof); }                       \
    BAR();                                                                      \
    /* I_b: read bf1(kt); stage B-hi(kt+1); G(rb0-1, cb0) */                    \
    RD_B(bf1, BB, 1);                                                           \
    if (SB1){ glds16(pB2 + O1, lds + BBn + 8192 + wof);                         \
              glds16(pB3 + O1, lds + BBn + 12288 + wof); }                      \
    __builtin_amdgcn_s_setprio(1);                                              \
    QG(0, 0, bf0);                                                              \
    __builtin_amdgcn_s_setprio(0);                                              \
    if ((WB) >= 0) VMW(WB);                                                     \
    BAR();                                                                      \
    /* I_c: G(rb0-1, cb1); read af<-A rb2-3(kt); stage A-hi(kt+1) */            \
    __builtin_amdgcn_s_setprio(1);                                              \
    QG(0, 1, bf1);                                                              \
    __builtin_amdgcn_s_setprio(0);                                              \
    RD_A(AB, 2);                                                                \
    if (SB1){ glds16(pA1 + O1, lds + ABn + 4096 + wof);                         \
              glds16(pA3 + O1, lds + ABn + 12288 + wof); }                      \
    BAR();                                                                      \
    /* I_d: stage A-lo(kt+2) into CURRENT A buf rows 0-63 & 128-191 (last      \
       reads drained 2 barriers ago); G(rb2-3, cb1); G(rb2-3, cb0) */           \
    if (SA2){ glds16(pA0 + O2, lds + AB + wof);                                 \
              glds16(pA2 + O2, lds + AB + 8192 + wof); }                        \
    __builtin_amdgcn_s_setprio(1);                                              \
    QG(2, 1, bf1);                                                              \
    QG(2, 0, bf0);                                                              \
    __builtin_amdgcn_s_setprio(0);                                              \
    if ((WD) >= 0) VMW(WD);                                                     \
    BAR();                                                                      \
  }while(0)

  for (int kt2 = 0; kt2 < NT - 2; kt2 += 2){
    TILE_P(0, 1, 1, 6, 4);
    TILE_P(1, 1, 1, 6, 4);
    pA0 += 128; pA1 += 128; pA2 += 128; pA3 += 128;
    pB0 += 128; pB1 += 128; pB2 += 128; pB3 += 128;
  }
  TILE_P(0, 1, 0, 6, 2);     // kt = NT-2: stages tile NT-1; drain thru B-hi(NT-1)
  TILE_P(1, 0, 0, 0, -1);    // kt = NT-1: compute only; drain A-hi before I_c
#undef TILE_P
#undef QG
#undef RD_A
#undef RD_B

  // ---- epilogue: C/D col = lane&31, row = (r&3) + 8*(r>>2) + 4*hi ----
  #pragma unroll
  for (int rb = 0; rb < 4; ++rb){
    const int rowbase = m0 + wr * 128 + rb * 32 + 4 * hi;
    #pragma unroll
    for (int cb = 0; cb < 2; ++cb){
      const int col = n0 + wc * 64 + cb * 32 + l31;
      #pragma unroll
      for (int r = 0; r < 16; ++r){
        const int row = rowbase + (r & 3) + 8 * (r >> 2);
        float v = acc[rb][cb][r];
        if constexpr (PHASE1){
          ((unsigned short*)Out)[(size_t)cp * M * Nd + (size_t)row * Nd + col] = f2b(gelu_fast(v));
        } else {
          ((float*)Out)[(size_t)p * M * Nd + (size_t)row * Nd + col] = v;
        }
      }
    }
  }
}

// ---------------- launch ----------------

extern "C" void kernel_launch(void* const* d_in, const int* in_sizes, int n_in,
                              void* d_out, int out_size, void* d_ws, size_t ws_size,
                              hipStream_t stream){
  const float* x  = (const float*)d_in[0];
  const float* w1 = (const float*)d_in[1];
  const float* b1 = (const float*)d_in[2];
  const float* w2 = (const float*)d_in[3];
  const float* b2 = (const float*)d_in[4];
  float* out = (float*)d_out;

  unsigned short* xb  = (unsigned short*)d_ws;
  unsigned short* w1t = (unsigned short*)((char*)d_ws + ((size_t)64  << 20));
  unsigned short* w2t = (unsigned short*)((char*)d_ws + ((size_t)128 << 20));
  unsigned short* hb  = (unsigned short*)((char*)d_ws + ((size_t)192 << 20));

  size_t avail = ws_size > ((size_t)192 << 20) ? ws_size - ((size_t)192 << 20) : 0;
  int ppc = (int)(avail / ((size_t)8 << 20));
  if (ppc > 32) ppc = 32;
  if (ppc < 1) return;

  cvt_x_kernel<<<2048, 256, 0, stream>>>(x, xb, 8 * 1024 * 1024);
  transpose_cvt<<<dim3(64, 16, 8), 256, 0, stream>>>(w1, w1t, 1024, 4096);
  transpose_cvt<<<dim3(16, 64, 8), 256, 0, stream>>>(w2, w2t, 4096, 1024);

  for (int p0 = 0; p0 < 32; p0 += ppc){
    int np = (32 - p0 < ppc) ? (32 - p0) : ppc;
    // GEMM1: h = gelu(xb @ w1t^T + b1)   [M=1024, K=1024, Nd=4096]
    gemm256<1><<<dim3(np * 4 * 16), 512, 0, stream>>>(xb, w1t, b1, hb, p0);
    // GEMM2: out = h @ w2t^T + b2        [M=1024, K=4096, Nd=1024]
    gemm256<0><<<dim3(np * 4 * 4),  512, 0, stream>>>(hb, w2t, b2, out, p0);
  }
}

// Round 11
// 685.028 us; speedup vs baseline: 3.0339x; 1.0153x over previous
//
#include <hip/hip_runtime.h>
#include <stdint.h>

// Experts MLP: out[b,e] = gelu(x[b,e] @ w1[e] + b1[e]) @ w2[e] + b2[e]
// B=4 E=8 N=1024 D=1024 H=4096.
// Round 11: r10 (32x32x16 MFMA, r8 sync skeleton) with the LDS swizzle key
// widened (row&7 -> (row^(row>>3))&7). r10's 2.5e7 bank conflicts came from
// lanes {x,x+8,x+16,x+24} (same lane&7) reading rows that share row&7 ->
// same stored chunk -> same 4-bank group. The wider key maps them to 4
// distinct chunks; the resulting (row,chunk) distribution matches the
// proven-zero-conflict 16x16 layout at every lane-group granularity.

typedef __attribute__((ext_vector_type(8))) short short8;
typedef __attribute__((ext_vector_type(16))) float f32x16;

__device__ __forceinline__ unsigned short f2b(float f){
  union { float f; unsigned int u; } v; v.f = f;
  unsigned int r = v.u + 0x7fffu + ((v.u >> 16) & 1u);   // RNE
  return (unsigned short)(r >> 16);
}

// tanh-form GELU via exp2/rcp (verified r3-r10)
__device__ __forceinline__ float gelu_fast(float v){
  float v2 = v * v;
  float w = v * (-2.302217529693f + -0.102943795894f * v2);
  float e = __builtin_amdgcn_exp2f(w);
  return v * __builtin_amdgcn_rcpf(1.0f + e);
}

__device__ __forceinline__ void glds16(const void* g, const void* l){
  __builtin_amdgcn_global_load_lds((const __attribute__((address_space(1))) uint32_t*)g,
                                   (__attribute__((address_space(3))) uint32_t*)l, 16, 0, 0);
}

#define BAR() do{ asm volatile("" ::: "memory"); __builtin_amdgcn_s_barrier(); asm volatile("" ::: "memory"); }while(0)
#define VMW(N) do{ if ((N)==6) asm volatile("s_waitcnt vmcnt(6)":::"memory"); \
  else if ((N)==4) asm volatile("s_waitcnt vmcnt(4)":::"memory"); \
  else if ((N)==2) asm volatile("s_waitcnt vmcnt(2)":::"memory"); \
  else if ((N)==0) asm volatile("s_waitcnt vmcnt(0)":::"memory"); }while(0)

// ---------------- prep kernels (verified r1-r10) ----------------

__global__ void cvt_x_kernel(const float* __restrict__ src, unsigned short* __restrict__ dst, int n4){
  int i = blockIdx.x * blockDim.x + threadIdx.x;
  int stride = gridDim.x * blockDim.x;
  for (; i < n4; i += stride){
    float4 v = ((const float4*)src)[i];
    ushort4 o;
    o.x = f2b(v.x); o.y = f2b(v.y); o.z = f2b(v.z); o.w = f2b(v.w);
    ((ushort4*)dst)[i] = o;
  }
}

__global__ void transpose_cvt(const float* __restrict__ src, unsigned short* __restrict__ dst, int R, int C){
  __shared__ float t[64][65];
  const int e = blockIdx.z;
  src += (size_t)e * R * C;
  dst += (size_t)e * R * C;
  const int r0 = blockIdx.y * 64, c0 = blockIdx.x * 64;
  const int tid = threadIdx.x;
  const int lr = tid >> 4;
  const int lc4 = (tid & 15) * 4;
  #pragma unroll
  for (int p2 = 0; p2 < 4; p2++){
    int r = lr + p2 * 16;
    float4 v = *(const float4*)(src + (size_t)(r0 + r) * C + (c0 + lc4));
    t[r][lc4+0] = v.x; t[r][lc4+1] = v.y; t[r][lc4+2] = v.z; t[r][lc4+3] = v.w;
  }
  __syncthreads();
  #pragma unroll
  for (int p2 = 0; p2 < 4; p2++){
    int c = lr + p2 * 16;
    ushort4 o;
    o.x = f2b(t[lc4+0][c]); o.y = f2b(t[lc4+1][c]);
    o.z = f2b(t[lc4+2][c]); o.w = f2b(t[lc4+3][c]);
    *(ushort4*)(dst + (size_t)(c0 + c) * R + (r0 + lc4)) = o;
  }
}

// ---------------- 256x256 8-phase GEMM, 32x32x16 MFMA ----------------
// LDS rows = 64 bf16 (8 x 16B chunks). Swizzle: chunk c of row r stored at
// LDS chunk c ^ k(r), k(r) = (r ^ (r>>3)) & 7. LDS linear + pre-swizzled
// global source (rule #21); reads apply the same key.
// LDS map (shorts): A buf0 @0, A buf1 @16384, B buf0 @32768, B buf1 @49152.
// 32x32x16 frags: A lane holds row (lane&31), k-chunk (ks*2 + (lane>>5)).
// C/D: col = lane&31, row = (reg&3) + 8*(reg>>2) + 4*(lane>>5)  [m74/m101].
// Wave tile 128x64 = 4 rowblocks(32) x 2 colblocks(32); 32 MFMA/wave/K-tile.
// Sync skeleton identical to r8/r10.

template<int PHASE1>
__global__ __launch_bounds__(512, 2) void gemm256(
    const unsigned short* __restrict__ A,
    const unsigned short* __restrict__ Bt,
    const float* __restrict__ bias,
    void* __restrict__ Out,
    int p0)
{
  constexpr int M  = 1024;
  constexpr int K  = PHASE1 ? 1024 : 4096;
  constexpr int Nd = PHASE1 ? 4096 : 1024;
  constexpr int TM = M / 256, TN = Nd / 256;
  constexpr int NT = K / 64;                 // 16 or 64 (even, >=4)

  const int cpx = gridDim.x >> 3;
  const int bid = (blockIdx.x & 7) * cpx + (blockIdx.x >> 3);
  const int tn = bid % TN;
  const int t2 = bid / TN;
  const int tm = t2 % TM;
  const int cp = t2 / TM;
  const int p  = p0 + cp, e = p & 7;
  const int m0 = tm * 256, n0 = tn * 256;

  const unsigned short* Ag = A  + (size_t)(PHASE1 ? p : cp) * M * K + (size_t)m0 * K;
  const unsigned short* Bg = Bt + (size_t)e * Nd * K + (size_t)n0 * K;
  const float*          bp = bias + (size_t)e * Nd;

  __shared__ __align__(16) unsigned short lds[65536];

  const int tid = threadIdx.x;
  const int w = tid >> 6, lane = tid & 63;
  const int wr = w >> 2, wc = w & 3;          // 2 x 4 waves; wave tile 128 x 64
  const int l31 = lane & 31, hi = lane >> 5;

  // staging: per-thread row within a 64-row block + swizzled chunk (shorts)
  const int trow = (w << 3) + (lane >> 3);                 // 0..63
  const int scol = (((lane & 7) ^ ((trow ^ (trow >> 3)) & 7)) << 3);
  const unsigned short* pA0 = Ag + (size_t)(trow       ) * K + scol;
  const unsigned short* pA1 = Ag + (size_t)(trow +  64) * K + scol;
  const unsigned short* pA2 = Ag + (size_t)(trow + 128) * K + scol;
  const unsigned short* pA3 = Ag + (size_t)(trow + 192) * K + scol;
  const unsigned short* pB0 = Bg + (size_t)(trow       ) * K + scol;
  const unsigned short* pB1 = Bg + (size_t)(trow +  64) * K + scol;
  const unsigned short* pB2 = Bg + (size_t)(trow + 128) * K + scol;
  const unsigned short* pB3 = Bg + (size_t)(trow + 192) * K + scol;
  const int wof = w << 9;                                  // LDS dest base (shorts)

  // frag-read per-thread constants (shorts).
  // row = base + l31, base % 32 == 0 -> k(row) = (l31&7) ^ (l31>>3) ^ ((base>>3)&4)
  const int rA32 = (wr * 128 + l31) << 6;                  // A row base offset
  const int rB32 = (wc * 64  + l31) << 6;                  // B row base offset
  const int kx = (l31 & 7) ^ (l31 >> 3);
  int cc[2][4];                                            // [rowblock parity][ks]
  #pragma unroll
  for (int ks = 0; ks < 4; ++ks){
    cc[0][ks] = ((((ks << 1) + hi) ^ kx) << 3);            // even 32-row block
    cc[1][ks] = cc[0][ks] ^ 32;                            // odd block: key ^ 4
  }

  // bias folded into accumulator init (col = lane-constant per colblock)
  float bv0 = bp[n0 + wc * 64      + l31];
  float bv1 = bp[n0 + wc * 64 + 32 + l31];

  f32x16 acc[4][2];
  #pragma unroll
  for (int rb = 0; rb < 4; rb++){ acc[rb][0] = (f32x16)(bv0); acc[rb][1] = (f32x16)(bv1); }

  // ---- prologue: tile0 (A+B) into buf0; A-lo(tile1) into buf1 (as r8) ----
  glds16(pA0, lds + wof);
  glds16(pA1, lds + wof + 4096);
  glds16(pA2, lds + wof + 8192);
  glds16(pA3, lds + wof + 12288);
  glds16(pB0, lds + wof + 32768);
  glds16(pB1, lds + wof + 32768 + 4096);
  glds16(pB2, lds + wof + 32768 + 8192);
  glds16(pB3, lds + wof + 32768 + 12288);
  glds16(pA0 + 64, lds + wof + 16384);            // A-lo(1): rows 0-63
  glds16(pA2 + 64, lds + wof + 16384 + 8192);     // A-lo(1): rows 128-191
  asm volatile("s_waitcnt vmcnt(2)" ::: "memory");
  BAR();

  short8 af[2][4], bf0[4], bf1[4];

  // read A rowblock pair {RB0, RB0+1} (8 b128); rowblock stride = 2048 shorts
#define RD_A(BASE, RB0) do{ _Pragma("unroll") for (int rb2 = 0; rb2 < 2; ++rb2) \
    _Pragma("unroll") for (int ks = 0; ks < 4; ++ks) \
      af[rb2][ks] = *(const short8*)(lds + (BASE) + rA32 + ((RB0) + rb2) * 2048 + cc[rb2][ks]); }while(0)
#define RD_B(DST, BASE, CB) do{ _Pragma("unroll") for (int ks = 0; ks < 4; ++ks) \
    DST[ks] = *(const short8*)(lds + (BASE) + rB32 + (CB) * 2048 + cc[CB][ks]); }while(0)
  // 8 MFMA: rowblocks {RB0,RB0+1} x colblock CB x 4 ksteps
#define QG(RB0, CB, BF) do{ _Pragma("unroll") for (int rb2 = 0; rb2 < 2; ++rb2) \
    _Pragma("unroll") for (int ks = 0; ks < 4; ++ks) \
      acc[(RB0) + rb2][CB] = __builtin_amdgcn_mfma_f32_32x32x16_bf16(af[rb2][ks], BF[ks], acc[(RB0) + rb2][CB], 0, 0, 0); }while(0)

  // One K-tile. SB1: stage tile kt+1 (B + A-hi). SA2: stage A-lo(kt+2).
  // WB/WD: vmcnt codes at I_b/I_d ends (-1 = none). Same codes as r8/r10.
#define TILE_P(CB_, SB1, SA2, WB, WD) do{                                       \
    constexpr int AB  = (CB_) * 16384;                                          \
    constexpr int BB  = 32768 + (CB_) * 16384;                                  \
    constexpr int ABn = ((CB_) ^ 1) * 16384;                                    \
    constexpr int BBn = 32768 + (((CB_) ^ 1) * 16384);                          \
    constexpr int O1  = (CB_) ? 128 : 64;                                       \
    constexpr int O2  = (CB_) ? 192 : 128;                                      \
    /* I_a: read af<-A rb0-1(kt), bf0(kt); stage B-lo(kt+1) */                  \
    RD_A(AB, 0);                                                                \
    RD_B(bf0, BB, 0);                                                           \
    if (SB1){ glds16(pB0 + O1, lds + BBn + wof);                                \
              glds16(pB1 + O1, lds + BBn + 4096 + wof); }                       \
    BAR();                                                                      \
    /* I_b: read bf1(kt); stage B-hi(kt+1); G(rb0-1, cb0) */                    \
    RD_B(bf1, BB, 1);                                                           \
    if (SB1){ glds16(pB2 + O1, lds + BBn + 8192 + wof);                         \
              glds16(pB3 + O1, lds + BBn + 12288 + wof); }                      \
    __builtin_amdgcn_s_setprio(1);                                              \
    QG(0, 0, bf0);                                                              \
    __builtin_amdgcn_s_setprio(0);                                              \
    if ((WB) >= 0) VMW(WB);                                                     \
    BAR();                                                                      \
    /* I_c: G(rb0-1, cb1); read af<-A rb2-3(kt); stage A-hi(kt+1) */            \
    __builtin_amdgcn_s_setprio(1);                                              \
    QG(0, 1, bf1);                                                              \
    __builtin_amdgcn_s_setprio(0);                                              \
    RD_A(AB, 2);                                                                \
    if (SB1){ glds16(pA1 + O1, lds + ABn + 4096 + wof);                         \
              glds16(pA3 + O1, lds + ABn + 12288 + wof); }                      \
    BAR();                                                                      \
    /* I_d: stage A-lo(kt+2) into CURRENT A buf rows 0-63 & 128-191 (last      \
       reads drained 2 barriers ago); G(rb2-3, cb1); G(rb2-3, cb0) */           \
    if (SA2){ glds16(pA0 + O2, lds + AB + wof);                                 \
              glds16(pA2 + O2, lds + AB + 8192 + wof); }                        \
    __builtin_amdgcn_s_setprio(1);                                              \
    QG(2, 1, bf1);                                                              \
    QG(2, 0, bf0);                                                              \
    __builtin_amdgcn_s_setprio(0);                                              \
    if ((WD) >= 0) VMW(WD);                                                     \
    BAR();                                                                      \
  }while(0)

  for (int kt2 = 0; kt2 < NT - 2; kt2 += 2){
    TILE_P(0, 1, 1, 6, 4);
    TILE_P(1, 1, 1, 6, 4);
    pA0 += 128; pA1 += 128; pA2 += 128; pA3 += 128;
    pB0 += 128; pB1 += 128; pB2 += 128; pB3 += 128;
  }
  TILE_P(0, 1, 0, 6, 2);     // kt = NT-2: stages tile NT-1; drain thru B-hi(NT-1)
  TILE_P(1, 0, 0, 0, -1);    // kt = NT-1: compute only; drain A-hi before I_c
#undef TILE_P
#undef QG
#undef RD_A
#undef RD_B

  // ---- epilogue: C/D col = lane&31, row = (r&3) + 8*(r>>2) + 4*hi ----
  #pragma unroll
  for (int rb = 0; rb < 4; ++rb){
    const int rowbase = m0 + wr * 128 + rb * 32 + 4 * hi;
    #pragma unroll
    for (int cb = 0; cb < 2; ++cb){
      const int col = n0 + wc * 64 + cb * 32 + l31;
      #pragma unroll
      for (int r = 0; r < 16; ++r){
        const int row = rowbase + (r & 3) + 8 * (r >> 2);
        float v = acc[rb][cb][r];
        if constexpr (PHASE1){
          ((unsigned short*)Out)[(size_t)cp * M * Nd + (size_t)row * Nd + col] = f2b(gelu_fast(v));
        } else {
          ((float*)Out)[(size_t)p * M * Nd + (size_t)row * Nd + col] = v;
        }
      }
    }
  }
}

// ---------------- launch ----------------

extern "C" void kernel_launch(void* const* d_in, const int* in_sizes, int n_in,
                              void* d_out, int out_size, void* d_ws, size_t ws_size,
                              hipStream_t stream){
  const float* x  = (const float*)d_in[0];
  const float* w1 = (const float*)d_in[1];
  const float* b1 = (const float*)d_in[2];
  const float* w2 = (const float*)d_in[3];
  const float* b2 = (const float*)d_in[4];
  float* out = (float*)d_out;

  unsigned short* xb  = (unsigned short*)d_ws;
  unsigned short* w1t = (unsigned short*)((char*)d_ws + ((size_t)64  << 20));
  unsigned short* w2t = (unsigned short*)((char*)d_ws + ((size_t)128 << 20));
  unsigned short* hb  = (unsigned short*)((char*)d_ws + ((size_t)192 << 20));

  size_t avail = ws_size > ((size_t)192 << 20) ? ws_size - ((size_t)192 << 20) : 0;
  int ppc = (int)(avail / ((size_t)8 << 20));
  if (ppc > 32) ppc = 32;
  if (ppc < 1) return;

  cvt_x_kernel<<<2048, 256, 0, stream>>>(x, xb, 8 * 1024 * 1024);
  transpose_cvt<<<dim3(64, 16, 8), 256, 0, stream>>>(w1, w1t, 1024, 4096);
  transpose_cvt<<<dim3(16, 64, 8), 256, 0, stream>>>(w2, w2t, 4096, 1024);

  for (int p0 = 0; p0 < 32; p0 += ppc){
    int np = (32 - p0 < ppc) ? (32 - p0) : ppc;
    // GEMM1: h = gelu(xb @ w1t^T + b1)   [M=1024, K=1024, Nd=4096]
    gemm256<1><<<dim3(np * 4 * 16), 512, 0, stream>>>(xb, w1t, b1, hb, p0);
    // GEMM2: out = h @ w2t^T + b2        [M=1024, K=4096, Nd=1024]
    gemm256<0><<<dim3(np * 4 * 4),  512, 0, stream>>>(hb, w2t, b2, out, p0);
  }
}

// Round 12
// 625.566 us; speedup vs baseline: 3.3223x; 1.0951x over previous
//
#include <hip/hip_runtime.h>
#include <stdint.h>

// Experts MLP: out[b,e] = gelu(x[b,e] @ w1[e] + b1[e]) @ w2[e] + b2[e]
// B=4 E=8 N=1024 D=1024 H=4096.
// Round 12: r4's verified 8-barrier skeleton (16x16x32, reads-before-barrier /
// MFMA-after) + m201's waitcnt discipline: per pre-MFMA barrier, pinned
// `s_waitcnt lgkmcnt(0)` + sched_barrier(0) so each 16-MFMA cluster is
// contiguous (no compiler-interleaved lgkm waits / hoisted MFMAs, rule #18);
// lgkmcnt(8) throttle before the 12-read phase's barrier (m201 optional).
// r10/r11's 32x32 detour closed (dependent-chain bound, net slower).

typedef __attribute__((ext_vector_type(8))) short short8;
typedef __attribute__((ext_vector_type(4))) float f32x4;

__device__ __forceinline__ unsigned short f2b(float f){
  union { float f; unsigned int u; } v; v.f = f;
  unsigned int r = v.u + 0x7fffu + ((v.u >> 16) & 1u);   // RNE
  return (unsigned short)(r >> 16);
}

// tanh-form GELU via exp2/rcp (verified r3-r11)
__device__ __forceinline__ float gelu_fast(float v){
  float v2 = v * v;
  float w = v * (-2.302217529693f + -0.102943795894f * v2);
  float e = __builtin_amdgcn_exp2f(w);
  return v * __builtin_amdgcn_rcpf(1.0f + e);
}

__device__ __forceinline__ void glds16(const void* g, const void* l){
  __builtin_amdgcn_global_load_lds((const __attribute__((address_space(1))) uint32_t*)g,
                                   (__attribute__((address_space(3))) uint32_t*)l, 16, 0, 0);
}

#define BAR() do{ asm volatile("" ::: "memory"); __builtin_amdgcn_s_barrier(); asm volatile("" ::: "memory"); }while(0)
// pinned drain before a pure MFMA cluster (m201 pattern; rule #18 fence)
#define LGKM0_PIN() do{ asm volatile("s_waitcnt lgkmcnt(0)" ::: "memory"); \
                        __builtin_amdgcn_sched_barrier(0); }while(0)

// ---------------- prep kernels (verified r1-r11) ----------------

__global__ void cvt_x_kernel(const float* __restrict__ src, unsigned short* __restrict__ dst, int n4){
  int i = blockIdx.x * blockDim.x + threadIdx.x;
  int stride = gridDim.x * blockDim.x;
  for (; i < n4; i += stride){
    float4 v = ((const float4*)src)[i];
    ushort4 o;
    o.x = f2b(v.x); o.y = f2b(v.y); o.z = f2b(v.z); o.w = f2b(v.w);
    ((ushort4*)dst)[i] = o;
  }
}

__global__ void transpose_cvt(const float* __restrict__ src, unsigned short* __restrict__ dst, int R, int C){
  __shared__ float t[64][65];
  const int e = blockIdx.z;
  src += (size_t)e * R * C;
  dst += (size_t)e * R * C;
  const int r0 = blockIdx.y * 64, c0 = blockIdx.x * 64;
  const int tid = threadIdx.x;
  const int lr = tid >> 4;
  const int lc4 = (tid & 15) * 4;
  #pragma unroll
  for (int p2 = 0; p2 < 4; p2++){
    int r = lr + p2 * 16;
    float4 v = *(const float4*)(src + (size_t)(r0 + r) * C + (c0 + lc4));
    t[r][lc4+0] = v.x; t[r][lc4+1] = v.y; t[r][lc4+2] = v.z; t[r][lc4+3] = v.w;
  }
  __syncthreads();
  #pragma unroll
  for (int p2 = 0; p2 < 4; p2++){
    int c = lr + p2 * 16;
    ushort4 o;
    o.x = f2b(t[lc4+0][c]); o.y = f2b(t[lc4+1][c]);
    o.z = f2b(t[lc4+2][c]); o.w = f2b(t[lc4+3][c]);
    *(ushort4*)(dst + (size_t)(c0 + c) * R + (r0 + lc4)) = o;
  }
}

// ---------------- 256x256 8-phase GEMM (r4 skeleton + m201 waits) ---------
// LDS rows = 64 bf16 (8 x 16B chunks); chunk c of row r at LDS chunk
// (c ^ (r&7)); LDS linear + pre-swizzled global source (rule #21).
// LDS map (shorts): A buf0 @0, A buf1 @16384, B buf0 @32768, B buf1 @49152.
// Per phase: [ds_reads for THIS phase's MFMA; stage issues; (lgkm throttle);
// BARRIER; lgkmcnt(0)+sched_barrier(0); setprio(1); 16 MFMA; setprio(0);
// BARRIER]. vmcnt(2) once per tile at ph3-end (audited r4: drains all of
// tile kt+1, leaves A-lo(kt+2) in flight).

template<int PHASE1>
__global__ __launch_bounds__(512, 2) void gemm256(
    const unsigned short* __restrict__ A,
    const unsigned short* __restrict__ Bt,
    const float* __restrict__ bias,
    void* __restrict__ Out,
    int p0)
{
  constexpr int M  = 1024;
  constexpr int K  = PHASE1 ? 1024 : 4096;
  constexpr int Nd = PHASE1 ? 4096 : 1024;
  constexpr int TM = M / 256, TN = Nd / 256;
  constexpr int NT = K / 64;                 // 16 or 64 (even, >=4)

  const int cpx = gridDim.x >> 3;
  const int bid = (blockIdx.x & 7) * cpx + (blockIdx.x >> 3);
  const int tn = bid % TN;
  const int t2 = bid / TN;
  const int tm = t2 % TM;
  const int cp = t2 / TM;
  const int p  = p0 + cp, e = p & 7;
  const int m0 = tm * 256, n0 = tn * 256;

  const unsigned short* Ag = A  + (size_t)(PHASE1 ? p : cp) * M * K + (size_t)m0 * K;
  const unsigned short* Bg = Bt + (size_t)e * Nd * K + (size_t)n0 * K;
  const float*          bp = bias + (size_t)e * Nd;

  __shared__ __align__(16) unsigned short lds[65536];

  const int tid = threadIdx.x;
  const int w = tid >> 6, lane = tid & 63;
  const int wr = w >> 2, wc = w & 3;          // 2 x 4 waves; wave tile 128 x 64
  const int c15 = lane & 15, q = lane >> 4;

  // staging: per-thread row within a 64-row block + swizzled chunk (shorts)
  const int trow = (w << 3) + (lane >> 3);                 // 0..63
  const int scol = ((lane & 7) ^ (trow & 7)) << 3;
  const unsigned short* pA0 = Ag + (size_t)(trow       ) * K + scol;
  const unsigned short* pA1 = Ag + (size_t)(trow +  64) * K + scol;
  const unsigned short* pA2 = Ag + (size_t)(trow + 128) * K + scol;
  const unsigned short* pA3 = Ag + (size_t)(trow + 192) * K + scol;
  const unsigned short* pB0 = Bg + (size_t)(trow       ) * K + scol;
  const unsigned short* pB1 = Bg + (size_t)(trow +  64) * K + scol;
  const unsigned short* pB2 = Bg + (size_t)(trow + 128) * K + scol;
  const unsigned short* pB3 = Bg + (size_t)(trow + 192) * K + scol;
  const int wof = w << 9;                                  // LDS dest base (shorts)

  // frag-read per-thread constants (shorts)
  const int rA64 = (wr * 128 + c15) << 6;
  const int rB64 = (wc * 64  + c15) << 6;
  const int cx0 = ( q      ^ (c15 & 7)) << 3;              // kk=0 chunk
  const int cx1 = ((q ^ 4) ^ (c15 & 7)) << 3;              // kk=1 chunk

  // bias folded into accumulator init
  float bv[4];
  #pragma unroll
  for (int nf = 0; nf < 4; ++nf) bv[nf] = bp[n0 + wc * 64 + nf * 16 + c15];

  f32x4 acc[8][4];
  #pragma unroll
  for (int i = 0; i < 8; i++)
    #pragma unroll
    for (int j = 0; j < 4; j++) acc[i][j] = (f32x4)(bv[j]);

  // ---- prologue: tile 0 into buf0 (A+B), tile 1 A rows 0..127 into buf1 ----
  glds16(pA0, lds + wof);
  glds16(pA1, lds + wof + 4096);
  glds16(pA2, lds + wof + 8192);
  glds16(pA3, lds + wof + 12288);
  glds16(pB0, lds + wof + 32768);
  glds16(pB1, lds + wof + 32768 + 4096);
  glds16(pB2, lds + wof + 32768 + 8192);
  glds16(pB3, lds + wof + 32768 + 12288);
  glds16(pA0 + 64, lds + wof + 16384);
  glds16(pA1 + 64, lds + wof + 16384 + 4096);
  asm volatile("s_waitcnt vmcnt(2)" ::: "memory");
  BAR();

  short8 af[4][2], bf0[2][2], bf1[2][2];

  // one K-tile body; CB compile-time. O1/O2 = elem offsets to tiles kt+1/kt+2
  // from the running pointers (which track tile kt2).
#define TILE_BODY(CB, PF1, PF2, VM) do{                                         \
    constexpr int AB  = (CB) * 16384;                                           \
    constexpr int BB  = 32768 + (CB) * 16384;                                   \
    constexpr int ABn = ((CB) ^ 1) * 16384;                                     \
    constexpr int BBn = 32768 + (((CB) ^ 1) * 16384);                           \
    constexpr int O1  = (CB) ? 128 : 64;                                        \
    constexpr int O2  = (CB) ? 192 : 128;                                       \
    /* phase 0: reads af(A-lo)+bf0 (12); stage A(kt+1) rows 128..255 */         \
    _Pragma("unroll")                                                           \
    for (int mf = 0; mf < 4; ++mf){                                             \
      af[mf][0] = *(const short8*)(lds + AB + rA64 + mf * 1024 + cx0);          \
      af[mf][1] = *(const short8*)(lds + AB + rA64 + mf * 1024 + cx1);          \
    }                                                                           \
    _Pragma("unroll")                                                           \
    for (int nf = 0; nf < 2; ++nf){                                             \
      bf0[nf][0] = *(const short8*)(lds + BB + rB64 + nf * 1024 + cx0);         \
      bf0[nf][1] = *(const short8*)(lds + BB + rB64 + nf * 1024 + cx1);         \
    }                                                                           \
    if (PF1){ glds16(pA2 + O1, lds + ABn + 8192 + wof);                         \
              glds16(pA3 + O1, lds + ABn + 12288 + wof); }                      \
    asm volatile("s_waitcnt lgkmcnt(8)" ::: "memory");  /* m201 throttle */     \
    BAR();                                                                      \
    LGKM0_PIN();                                                                \
    __builtin_amdgcn_s_setprio(1);                                              \
    _Pragma("unroll")                                                           \
    for (int mf = 0; mf < 4; ++mf)                                              \
      _Pragma("unroll")                                                         \
      for (int nf = 0; nf < 2; ++nf){                                           \
        acc[mf][nf] = __builtin_amdgcn_mfma_f32_16x16x32_bf16(af[mf][0], bf0[nf][0], acc[mf][nf], 0, 0, 0); \
        acc[mf][nf] = __builtin_amdgcn_mfma_f32_16x16x32_bf16(af[mf][1], bf0[nf][1], acc[mf][nf], 0, 0, 0); \
      }                                                                         \
    __builtin_amdgcn_s_setprio(0);                                              \
    BAR();                                                                      \
    /* phase 1: reads bf1 (4); stage B(kt+1) rows 0..127 */                     \
    _Pragma("unroll")                                                           \
    for (int nf = 0; nf < 2; ++nf){                                             \
      bf1[nf][0] = *(const short8*)(lds + BB + rB64 + 2048 + nf * 1024 + cx0);  \
      bf1[nf][1] = *(const short8*)(lds + BB + rB64 + 2048 + nf * 1024 + cx1);  \
    }                                                                           \
    if (PF1){ glds16(pB0 + O1, lds + BBn + wof);                                \
              glds16(pB1 + O1, lds + BBn + 4096 + wof); }                       \
    BAR();                                                                      \
    LGKM0_PIN();                                                                \
    __builtin_amdgcn_s_setprio(1);                                              \
    _Pragma("unroll")                                                           \
    for (int mf = 0; mf < 4; ++mf)                                              \
      _Pragma("unroll")                                                         \
      for (int nf = 0; nf < 2; ++nf){                                           \
        acc[mf][2+nf] = __builtin_amdgcn_mfma_f32_16x16x32_bf16(af[mf][0], bf1[nf][0], acc[mf][2+nf], 0, 0, 0); \
        acc[mf][2+nf] = __builtin_amdgcn_mfma_f32_16x16x32_bf16(af[mf][1], bf1[nf][1], acc[mf][2+nf], 0, 0, 0); \
      }                                                                         \
    __builtin_amdgcn_s_setprio(0);                                              \
    BAR();                                                                      \
    /* phase 2: reads af<-A-hi (8); stage B(kt+1) rows 128..255 */              \
    _Pragma("unroll")                                                           \
    for (int mf = 0; mf < 4; ++mf){                                             \
      af[mf][0] = *(const short8*)(lds + AB + rA64 + 4096 + mf * 1024 + cx0);   \
      af[mf][1] = *(const short8*)(lds + AB + rA64 + 4096 + mf * 1024 + cx1);   \
    }                                                                           \
    if (PF1){ glds16(pB2 + O1, lds + BBn + 8192 + wof);                         \
              glds16(pB3 + O1, lds + BBn + 12288 + wof); }                      \
    BAR();                                                                      \
    LGKM0_PIN();                                                                \
    __builtin_amdgcn_s_setprio(1);                                              \
    _Pragma("unroll")                                                           \
    for (int mf = 0; mf < 4; ++mf)                                              \
      _Pragma("unroll")                                                         \
      for (int nf = 0; nf < 2; ++nf){                                           \
        acc[4+mf][2+nf] = __builtin_amdgcn_mfma_f32_16x16x32_bf16(af[mf][0], bf1[nf][0], acc[4+mf][2+nf], 0, 0, 0); \
        acc[4+mf][2+nf] = __builtin_amdgcn_mfma_f32_16x16x32_bf16(af[mf][1], bf1[nf][1], acc[4+mf][2+nf], 0, 0, 0); \
      }                                                                         \
    __builtin_amdgcn_s_setprio(0);                                              \
    BAR();                                                                      \
    /* phase 3: reg-only; stage A(kt+2) rows 0..127 into CURRENT A buf */       \
    if (PF2){ glds16(pA0 + O2, lds + AB + wof);                                 \
              glds16(pA1 + O2, lds + AB + 4096 + wof); }                        \
    BAR();                                                                      \
    __builtin_amdgcn_sched_barrier(0);                                          \
    __builtin_amdgcn_s_setprio(1);                                              \
    _Pragma("unroll")                                                           \
    for (int mf = 0; mf < 4; ++mf)                                              \
      _Pragma("unroll")                                                         \
      for (int nf = 0; nf < 2; ++nf){                                           \
        acc[4+mf][nf] = __builtin_amdgcn_mfma_f32_16x16x32_bf16(af[mf][0], bf0[nf][0], acc[4+mf][nf], 0, 0, 0); \
        acc[4+mf][nf] = __builtin_amdgcn_mfma_f32_16x16x32_bf16(af[mf][1], bf0[nf][1], acc[4+mf][nf], 0, 0, 0); \
      }                                                                         \
    __builtin_amdgcn_s_setprio(0);                                              \
    if ((VM) >= 0){                                                             \
      if ((VM) == 2) asm volatile("s_waitcnt vmcnt(2)" ::: "memory");           \
      else           asm volatile("s_waitcnt vmcnt(0)" ::: "memory");           \
    }                                                                           \
    BAR();                                                                      \
  }while(0)

  for (int kt2 = 0; kt2 + 2 < NT; kt2 += 2){
    TILE_BODY(0, 1, 1, 2);
    TILE_BODY(1, 1, 1, 2);
    pA0 += 128; pA1 += 128; pA2 += 128; pA3 += 128;
    pB0 += 128; pB1 += 128; pB2 += 128; pB3 += 128;
  }
  TILE_BODY(0, 1, 0, 0);    // tile NT-2: stage tile NT-1, drain
  TILE_BODY(1, 0, 0, -1);   // tile NT-1: compute only
#undef TILE_BODY

  // ---- epilogue: C/D layout col = lane&15, row = (lane>>4)*4 + r ----
  #pragma unroll
  for (int mf = 0; mf < 8; ++mf){
    const int row = m0 + wr * 128 + mf * 16 + q * 4;
    #pragma unroll
    for (int nf = 0; nf < 4; ++nf){
      const int col = n0 + wc * 64 + nf * 16 + c15;
      #pragma unroll
      for (int r = 0; r < 4; ++r){
        float v = acc[mf][nf][r];
        if constexpr (PHASE1){
          ((unsigned short*)Out)[(size_t)cp * M * Nd + (size_t)(row + r) * Nd + col] = f2b(gelu_fast(v));
        } else {
          ((float*)Out)[(size_t)p * M * Nd + (size_t)(row + r) * Nd + col] = v;
        }
      }
    }
  }
}

// ---------------- launch ----------------

extern "C" void kernel_launch(void* const* d_in, const int* in_sizes, int n_in,
                              void* d_out, int out_size, void* d_ws, size_t ws_size,
                              hipStream_t stream){
  const float* x  = (const float*)d_in[0];
  const float* w1 = (const float*)d_in[1];
  const float* b1 = (const float*)d_in[2];
  const float* w2 = (const float*)d_in[3];
  const float* b2 = (const float*)d_in[4];
  float* out = (float*)d_out;

  unsigned short* xb  = (unsigned short*)d_ws;
  unsigned short* w1t = (unsigned short*)((char*)d_ws + ((size_t)64  << 20));
  unsigned short* w2t = (unsigned short*)((char*)d_ws + ((size_t)128 << 20));
  unsigned short* hb  = (unsigned short*)((char*)d_ws + ((size_t)192 << 20));

  size_t avail = ws_size > ((size_t)192 << 20) ? ws_size - ((size_t)192 << 20) : 0;
  int ppc = (int)(avail / ((size_t)8 << 20));
  if (ppc > 32) ppc = 32;
  if (ppc < 1) return;

  cvt_x_kernel<<<2048, 256, 0, stream>>>(x, xb, 8 * 1024 * 1024);
  transpose_cvt<<<dim3(64, 16, 8), 256, 0, stream>>>(w1, w1t, 1024, 4096);
  transpose_cvt<<<dim3(16, 64, 8), 256, 0, stream>>>(w2, w2t, 4096, 1024);

  for (int p0 = 0; p0 < 32; p0 += ppc){
    int np = (32 - p0 < ppc) ? (32 - p0) : ppc;
    // GEMM1: h = gelu(xb @ w1t^T + b1)   [M=1024, K=1024, Nd=4096]
    gemm256<1><<<dim3(np * 4 * 16), 512, 0, stream>>>(xb, w1t, b1, hb, p0);
    // GEMM2: out = h @ w2t^T + b2        [M=1024, K=4096, Nd=1024]
    gemm256<0><<<dim3(np * 4 * 4),  512, 0, stream>>>(hb, w2t, b2, out, p0);
  }
}